// Round 3
// baseline (920.829 us; speedup 1.0000x reference)
//
#include <hip/hip_runtime.h>
#include <hip/hip_bf16.h>

#define D_IN   128
#define D_OUT  64
#define TILE_R 16

#define NPB    128                 // nodes per bucket
#define NB     782                 // ceil(100000/128)
#define CAP    2432                // slots per bucket region (mean 2046, +8.5 sigma)
#define CHUNK  4096                // edges per bin block

// ---------------------------------------------------------------------------
// Kernel 1: data = h @ W^T + b ; s = data @ a_src ; t = data @ a_dst
// 4 waves x 4 rows each, float4 broadcasts of h from LDS.
// ---------------------------------------------------------------------------
__global__ __launch_bounds__(256) void proj_kernel(
    const float* __restrict__ h, const float* __restrict__ Ww,
    const float* __restrict__ Wb, const float* __restrict__ a,
    float* __restrict__ data, float* __restrict__ s_out, float* __restrict__ t_out,
    int n)
{
    __shared__ float  wt[D_IN][D_OUT + 1];     // W transposed, padded
    __shared__ float4 hs4[TILE_R][D_IN / 4];   // h tile as float4

    const int tid = threadIdx.x;

    for (int i = tid; i < D_OUT * D_IN; i += 256) {
        int c = i >> 7;
        int k = i & (D_IN - 1);
        wt[k][c] = Ww[i];
    }

    const int r0 = blockIdx.x * TILE_R;
    for (int i = tid; i < TILE_R * (D_IN / 4); i += 256) {
        int r  = i >> 5;
        int kq = i & 31;
        float4 v = make_float4(0.f, 0.f, 0.f, 0.f);
        if (r0 + r < n)
            v = ((const float4*)h)[(size_t)(r0 + r) * (D_IN / 4) + kq];
        hs4[r][kq] = v;
    }
    __syncthreads();

    const int c    = tid & 63;
    const int wave = tid >> 6;
    const int rb   = wave * 4;          // 4 rows per wave
    const float a_src_c = a[c];
    const float a_dst_c = a[D_OUT + c];
    const float bias_c  = Wb[c];

    float acc0 = 0.f, acc1 = 0.f, acc2 = 0.f, acc3 = 0.f;
    #pragma unroll
    for (int kq = 0; kq < D_IN / 4; ++kq) {
        const float w0 = wt[4 * kq + 0][c];
        const float w1 = wt[4 * kq + 1][c];
        const float w2 = wt[4 * kq + 2][c];
        const float w3 = wt[4 * kq + 3][c];
        const float4 h0 = hs4[rb + 0][kq];
        const float4 h1 = hs4[rb + 1][kq];
        const float4 h2 = hs4[rb + 2][kq];
        const float4 h3 = hs4[rb + 3][kq];
        acc0 = fmaf(h0.x, w0, fmaf(h0.y, w1, fmaf(h0.z, w2, fmaf(h0.w, w3, acc0))));
        acc1 = fmaf(h1.x, w0, fmaf(h1.y, w1, fmaf(h1.z, w2, fmaf(h1.w, w3, acc1))));
        acc2 = fmaf(h2.x, w0, fmaf(h2.y, w1, fmaf(h2.z, w2, fmaf(h2.w, w3, acc2))));
        acc3 = fmaf(h3.x, w0, fmaf(h3.y, w1, fmaf(h3.z, w2, fmaf(h3.w, w3, acc3))));
    }

    float accs[4] = {acc0 + bias_c, acc1 + bias_c, acc2 + bias_c, acc3 + bias_c};
    #pragma unroll
    for (int q = 0; q < 4; ++q) {
        const int r = r0 + rb + q;
        const float acc = accs[q];
        if (r < n) data[(size_t)r * D_OUT + c] = acc;

        float sp = acc * a_src_c;
        float tp = acc * a_dst_c;
        #pragma unroll
        for (int off = 32; off > 0; off >>= 1) {
            sp += __shfl_xor(sp, off);
            tp += __shfl_xor(tp, off);
        }
        if (c == 0 && r < n) { s_out[r] = sp; t_out[r] = tp; }
    }
}

// ---------------------------------------------------------------------------
// Binning: edges -> per-bucket regions. One block per 4096-edge chunk.
// Records: ((e0 & 127) << 17) | e1
// ---------------------------------------------------------------------------
__global__ __launch_bounds__(256) void bin_kernel(
    const int* __restrict__ e0a, const int* __restrict__ e1a,
    int* __restrict__ cursor, unsigned int* __restrict__ region, int ne)
{
    __shared__ int cnt[NB];

    const int tid = threadIdx.x;
    const int base = blockIdx.x * CHUNK;

    for (int i = tid; i < NB; i += 256) cnt[i] = 0;
    __syncthreads();

    int          bj[16];
    unsigned int rc[16];

    // Phase 1: load + count
    #pragma unroll
    for (int j = 0; j < 16; ++j) {
        const int i = base + j * 256 + tid;
        if (i < ne) {
            const int u = e0a[i];
            const int v = e1a[i];
            bj[j] = u >> 7;
            rc[j] = ((unsigned int)(u & (NPB - 1)) << 17) | (unsigned int)v;
            atomicAdd(&cnt[bj[j]], 1);
        } else {
            bj[j] = -1;
            rc[j] = 0u;
        }
    }
    __syncthreads();

    // Phase 2: reserve global ranges; cnt[b] becomes the running cursor
    for (int b = tid; b < NB; b += 256) {
        const int c = cnt[b];
        int gbase = 0;
        if (c > 0) gbase = atomicAdd(&cursor[b], c);
        cnt[b] = gbase;
    }
    __syncthreads();

    // Phase 3: write records
    #pragma unroll
    for (int j = 0; j < 16; ++j) {
        if (bj[j] >= 0) {
            const int p = atomicAdd(&cnt[bj[j]], 1);
            if (p < CAP)
                region[(size_t)bj[j] * CAP + p] = rc[j];
        }
    }
}

// ---------------------------------------------------------------------------
// Aggregation: one block per bucket. LDS accumulators, lane = feature.
// ---------------------------------------------------------------------------
__global__ __launch_bounds__(256) void agg_kernel(
    const unsigned int* __restrict__ region, const int* __restrict__ cursor,
    const float* __restrict__ s, const float* __restrict__ t,
    const float* __restrict__ data, float* __restrict__ out, int n)
{
    __shared__ float acc[NPB * D_OUT];   // 32 KB
    __shared__ float wsum[NPB];
    __shared__ float s_lds[NPB];

    const int b   = blockIdx.x;
    const int u0  = b * NPB;
    const int tid = threadIdx.x;

    for (int i = tid; i < NPB * D_OUT; i += 256) acc[i] = 0.f;
    for (int i = tid; i < NPB; i += 256) {
        wsum[i] = 0.f;
        const int u = u0 + i;
        s_lds[i] = (u < n) ? s[u] : 0.f;
    }
    __syncthreads();

    const int cnt  = min(cursor[b], CAP);
    const int lane = tid & 63;
    const int wv   = tid >> 6;
    const unsigned int* reg = region + (size_t)b * CAP;

    int j = wv;
    for (; j + 4 < cnt; j += 8) {
        const unsigned int r0_ = reg[j];
        const unsigned int r1_ = reg[j + 4];
        const int ul0 = r0_ >> 17, v0 = r0_ & 0x1FFFF;
        const int ul1 = r1_ >> 17, v1 = r1_ & 0x1FFFF;
        const float d0 = data[(size_t)v0 * D_OUT + lane];
        const float d1 = data[(size_t)v1 * D_OUT + lane];
        const float raw0 = s_lds[ul0] + t[v0];
        const float raw1 = s_lds[ul1] + t[v1];
        const float l0 = raw0 > 0.f ? raw0 : 0.2f * raw0;
        const float l1 = raw1 > 0.f ? raw1 : 0.2f * raw1;
        const float w0 = __expf(l0 * 0.125f);
        const float w1 = __expf(l1 * 0.125f);
        atomicAdd(&acc[(ul0 << 6) + lane], w0 * d0);
        atomicAdd(&acc[(ul1 << 6) + lane], w1 * d1);
        if (lane == 0) {
            atomicAdd(&wsum[ul0], w0);
            atomicAdd(&wsum[ul1], w1);
        }
    }
    for (; j < cnt; j += 4) {
        const unsigned int r0_ = reg[j];
        const int ul0 = r0_ >> 17, v0 = r0_ & 0x1FFFF;
        const float d0 = data[(size_t)v0 * D_OUT + lane];
        const float raw0 = s_lds[ul0] + t[v0];
        const float l0 = raw0 > 0.f ? raw0 : 0.2f * raw0;
        const float w0 = __expf(l0 * 0.125f);
        atomicAdd(&acc[(ul0 << 6) + lane], w0 * d0);
        if (lane == 0) atomicAdd(&wsum[ul0], w0);
    }
    __syncthreads();

    for (int ul = wv; ul < NPB; ul += 4) {
        const int u = u0 + ul;
        if (u >= n) break;
        const float rs = wsum[ul];
        const float o = (rs == 0.f) ? data[(size_t)u * D_OUT + lane]
                                    : acc[(ul << 6) + lane] / rs;
        out[(size_t)u * D_OUT + lane] = o;
    }
}

extern "C" void kernel_launch(void* const* d_in, const int* in_sizes, int n_in,
                              void* d_out, int out_size, void* d_ws, size_t ws_size,
                              hipStream_t stream)
{
    const float* h    = (const float*)d_in[0];
    const int*   edge = (const int*)d_in[1];
    const float* Ww   = (const float*)d_in[2];
    const float* Wb   = (const float*)d_in[3];
    const float* a    = (const float*)d_in[4];

    const int n  = in_sizes[0] / D_IN;    // 100000
    const int ne = in_sizes[1] / 2;       // 1600000

    const int* e0a = edge;
    const int* e1a = edge + ne;
    float* out = (float*)d_out;

    char* wsp = (char*)d_ws;
    float* data   = (float*)wsp;   wsp += (size_t)n * D_OUT * sizeof(float);
    float* s      = (float*)wsp;   wsp += (size_t)n * sizeof(float);
    float* t      = (float*)wsp;   wsp += (size_t)n * sizeof(float);
    int*   cursor = (int*)wsp;     wsp += (size_t)NB * sizeof(int);
    unsigned int* region = (unsigned int*)wsp; wsp += (size_t)NB * CAP * sizeof(unsigned int);

    hipMemsetAsync(cursor, 0, (size_t)NB * sizeof(int), stream);

    proj_kernel<<<(n + TILE_R - 1) / TILE_R, 256, 0, stream>>>(
        h, Ww, Wb, a, data, s, t, n);

    bin_kernel<<<(ne + CHUNK - 1) / CHUNK, 256, 0, stream>>>(
        e0a, e1a, cursor, region, ne);

    agg_kernel<<<NB, 256, 0, stream>>>(
        region, cursor, s, t, data, out, n);
}

// Round 4
// 855.300 us; speedup vs baseline: 1.0766x; 1.0766x over previous
//
#include <hip/hip_runtime.h>
#include <hip/hip_bf16.h>

#define D_IN   128
#define D_OUT  64
#define TILE_R 16

#define CB_NODES  1024      // nodes per coarse bucket
#define FB_NODES  64        // nodes per fine bucket
#define FB_PER_CB 16
#define CAP1      20480     // coarse region slots (mean ~16327, sigma ~128)
#define CAP2      1536      // fine region slots   (mean ~1024,  sigma ~32)
#define CHUNK1    2048      // edges per bin1 block
#define CHUNK2    2048      // records per bin2 sub-pass

// ---------------------------------------------------------------------------
// Kernel 1: data = h @ W^T + b ; s = data @ a_src ; t = data @ a_dst
// ---------------------------------------------------------------------------
__global__ __launch_bounds__(256) void proj_kernel(
    const float* __restrict__ h, const float* __restrict__ Ww,
    const float* __restrict__ Wb, const float* __restrict__ a,
    float* __restrict__ data, float* __restrict__ s_out, float* __restrict__ t_out,
    int n)
{
    __shared__ float  wt[D_IN][D_OUT + 1];
    __shared__ float4 hs4[TILE_R][D_IN / 4];

    const int tid = threadIdx.x;

    for (int i = tid; i < D_OUT * D_IN; i += 256) {
        int c = i >> 7;
        int k = i & (D_IN - 1);
        wt[k][c] = Ww[i];
    }

    const int r0 = blockIdx.x * TILE_R;
    for (int i = tid; i < TILE_R * (D_IN / 4); i += 256) {
        int r  = i >> 5;
        int kq = i & 31;
        float4 v = make_float4(0.f, 0.f, 0.f, 0.f);
        if (r0 + r < n)
            v = ((const float4*)h)[(size_t)(r0 + r) * (D_IN / 4) + kq];
        hs4[r][kq] = v;
    }
    __syncthreads();

    const int c    = tid & 63;
    const int wave = tid >> 6;
    const int rb   = wave * 4;
    const float a_src_c = a[c];
    const float a_dst_c = a[D_OUT + c];
    const float bias_c  = Wb[c];

    float acc0 = 0.f, acc1 = 0.f, acc2 = 0.f, acc3 = 0.f;
    #pragma unroll
    for (int kq = 0; kq < D_IN / 4; ++kq) {
        const float w0 = wt[4 * kq + 0][c];
        const float w1 = wt[4 * kq + 1][c];
        const float w2 = wt[4 * kq + 2][c];
        const float w3 = wt[4 * kq + 3][c];
        const float4 h0 = hs4[rb + 0][kq];
        const float4 h1 = hs4[rb + 1][kq];
        const float4 h2 = hs4[rb + 2][kq];
        const float4 h3 = hs4[rb + 3][kq];
        acc0 = fmaf(h0.x, w0, fmaf(h0.y, w1, fmaf(h0.z, w2, fmaf(h0.w, w3, acc0))));
        acc1 = fmaf(h1.x, w0, fmaf(h1.y, w1, fmaf(h1.z, w2, fmaf(h1.w, w3, acc1))));
        acc2 = fmaf(h2.x, w0, fmaf(h2.y, w1, fmaf(h2.z, w2, fmaf(h2.w, w3, acc2))));
        acc3 = fmaf(h3.x, w0, fmaf(h3.y, w1, fmaf(h3.z, w2, fmaf(h3.w, w3, acc3))));
    }

    float accs[4] = {acc0 + bias_c, acc1 + bias_c, acc2 + bias_c, acc3 + bias_c};
    #pragma unroll
    for (int q = 0; q < 4; ++q) {
        const int r = r0 + rb + q;
        const float acc = accs[q];
        if (r < n) data[(size_t)r * D_OUT + c] = acc;

        float sp = acc * a_src_c;
        float tp = acc * a_dst_c;
        #pragma unroll
        for (int off = 32; off > 0; off >>= 1) {
            sp += __shfl_xor(sp, off);
            tp += __shfl_xor(tp, off);
        }
        if (c == 0 && r < n) { s_out[r] = sp; t_out[r] = tp; }
    }
}

// ---------------------------------------------------------------------------
// Level-1 binning: edges -> 98 coarse buckets. Record = (u_local10 << 17) | e1
// ---------------------------------------------------------------------------
__global__ __launch_bounds__(256) void bin1_kernel(
    const int* __restrict__ e0a, const int* __restrict__ e1a,
    int* __restrict__ cursor1, unsigned int* __restrict__ region1, int ne)
{
    __shared__ int cnt[128];
    __shared__ int basev[128];

    const int tid  = threadIdx.x;
    const int base = blockIdx.x * CHUNK1;

    for (int i = tid; i < 128; i += 256) cnt[i] = 0;
    __syncthreads();

    int bj[8]; unsigned rc[8];
    #pragma unroll
    for (int j = 0; j < 8; ++j) {
        const int i = base + j * 256 + tid;
        if (i < ne) {
            const int u = e0a[i];
            const int v = e1a[i];
            bj[j] = u >> 10;
            rc[j] = ((unsigned)(u & (CB_NODES - 1)) << 17) | (unsigned)v;
            atomicAdd(&cnt[bj[j]], 1);
        } else bj[j] = -1;
    }
    __syncthreads();

    for (int b = tid; b < 128; b += 256) {
        const int c = cnt[b];
        basev[b] = (c > 0) ? atomicAdd(&cursor1[b], c) : 0;
        cnt[b] = 0;
    }
    __syncthreads();

    #pragma unroll
    for (int j = 0; j < 8; ++j) {
        if (bj[j] >= 0) {
            const int p = basev[bj[j]] + atomicAdd(&cnt[bj[j]], 1);
            if (p < CAP1) region1[(size_t)bj[j] * CAP1 + p] = rc[j];
        }
    }
}

// ---------------------------------------------------------------------------
// Level-2 binning: each coarse region -> 16 fine buckets of 64 nodes.
// 8 blocks per coarse bucket. Record = (ul6 << 17) | e1
// ---------------------------------------------------------------------------
__global__ __launch_bounds__(256) void bin2_kernel(
    const int* __restrict__ cursor1, const unsigned int* __restrict__ region1,
    int* __restrict__ cursor2, unsigned int* __restrict__ region2)
{
    const int b = blockIdx.x >> 3;
    const int c = blockIdx.x & 7;
    const int cnt1 = min(cursor1[b], CAP1);
    const int lo = (cnt1 * c) >> 3;
    const int hi = (cnt1 * (c + 1)) >> 3;
    const unsigned int* reg = region1 + (size_t)b * CAP1;

    __shared__ int cnt[FB_PER_CB];
    __shared__ int basev[FB_PER_CB];
    const int tid = threadIdx.x;

    for (int start = lo; start < hi; start += CHUNK2) {
        if (tid < FB_PER_CB) cnt[tid] = 0;
        __syncthreads();

        int fj[8]; unsigned rc[8];
        #pragma unroll
        for (int j = 0; j < 8; ++j) {
            const int i = start + j * 256 + tid;
            if (i < hi) {
                const unsigned r = reg[i];
                const int ulocal = (int)(r >> 17);
                fj[j] = ulocal >> 6;
                rc[j] = ((unsigned)(ulocal & (FB_NODES - 1)) << 17) | (r & 0x1FFFFu);
                atomicAdd(&cnt[fj[j]], 1);
            } else fj[j] = -1;
        }
        __syncthreads();

        if (tid < FB_PER_CB) {
            const int cc = cnt[tid];
            basev[tid] = (cc > 0) ? atomicAdd(&cursor2[b * FB_PER_CB + tid], cc) : 0;
            cnt[tid] = 0;
        }
        __syncthreads();

        #pragma unroll
        for (int j = 0; j < 8; ++j) {
            if (fj[j] >= 0) {
                const int p = basev[fj[j]] + atomicAdd(&cnt[fj[j]], 1);
                const int gfb = b * FB_PER_CB + fj[j];
                if (p < CAP2) region2[(size_t)gfb * CAP2 + p] = rc[j];
            }
        }
        __syncthreads();
    }
}

// ---------------------------------------------------------------------------
// Aggregation: one block per fine bucket (64 nodes). LDS accumulators.
// Wave loads 64 records coalesced, shfl-broadcasts, 4 gathers in flight.
// ---------------------------------------------------------------------------
__global__ __launch_bounds__(256) void agg_kernel(
    const int* __restrict__ cursor2, const unsigned int* __restrict__ region2,
    const float* __restrict__ s, const float* __restrict__ t,
    const float* __restrict__ data, float* __restrict__ out, int n)
{
    __shared__ float acc[FB_NODES * D_OUT];   // 16 KB
    __shared__ float wsum[FB_NODES];
    __shared__ float s_lds[FB_NODES];

    const int fb   = blockIdx.x;
    const int u0   = fb * FB_NODES;
    const int tid  = threadIdx.x;
    const int lane = tid & 63;
    const int wv   = tid >> 6;

    for (int i = tid; i < FB_NODES * D_OUT; i += 256) acc[i] = 0.f;
    if (tid < FB_NODES) {
        wsum[tid] = 0.f;
        const int u = u0 + tid;
        s_lds[tid] = (u < n) ? s[u] : 0.f;
    }
    __syncthreads();

    const int cnt = min(cursor2[fb], CAP2);
    const unsigned int* reg = region2 + (size_t)fb * CAP2;

    for (int rbase = wv * 64; rbase < cnt; rbase += 256) {
        const int kmax = min(64, cnt - rbase);
        const unsigned rec = (lane < kmax) ? reg[rbase + lane] : 0u;
        int k = 0;
        for (; k + 4 <= kmax; k += 4) {
            const unsigned r0 = __shfl(rec, k);
            const unsigned r1 = __shfl(rec, k + 1);
            const unsigned r2 = __shfl(rec, k + 2);
            const unsigned r3 = __shfl(rec, k + 3);
            const int v0 = r0 & 0x1FFFF, ul0 = r0 >> 17;
            const int v1 = r1 & 0x1FFFF, ul1 = r1 >> 17;
            const int v2 = r2 & 0x1FFFF, ul2 = r2 >> 17;
            const int v3 = r3 & 0x1FFFF, ul3 = r3 >> 17;

            const float d0 = data[(size_t)v0 * D_OUT + lane];
            const float d1 = data[(size_t)v1 * D_OUT + lane];
            const float d2 = data[(size_t)v2 * D_OUT + lane];
            const float d3 = data[(size_t)v3 * D_OUT + lane];
            const float t0 = t[v0];
            const float t1 = t[v1];
            const float t2 = t[v2];
            const float t3 = t[v3];

            const float raw0 = s_lds[ul0] + t0;
            const float raw1 = s_lds[ul1] + t1;
            const float raw2 = s_lds[ul2] + t2;
            const float raw3 = s_lds[ul3] + t3;
            const float l0 = raw0 > 0.f ? raw0 : 0.2f * raw0;
            const float l1 = raw1 > 0.f ? raw1 : 0.2f * raw1;
            const float l2 = raw2 > 0.f ? raw2 : 0.2f * raw2;
            const float l3 = raw3 > 0.f ? raw3 : 0.2f * raw3;
            const float w0 = __expf(l0 * 0.125f);
            const float w1 = __expf(l1 * 0.125f);
            const float w2 = __expf(l2 * 0.125f);
            const float w3 = __expf(l3 * 0.125f);

            atomicAdd(&acc[(ul0 << 6) + lane], w0 * d0);
            atomicAdd(&acc[(ul1 << 6) + lane], w1 * d1);
            atomicAdd(&acc[(ul2 << 6) + lane], w2 * d2);
            atomicAdd(&acc[(ul3 << 6) + lane], w3 * d3);
            if (lane == 0) {
                atomicAdd(&wsum[ul0], w0);
                atomicAdd(&wsum[ul1], w1);
                atomicAdd(&wsum[ul2], w2);
                atomicAdd(&wsum[ul3], w3);
            }
        }
        for (; k < kmax; ++k) {
            const unsigned r0 = __shfl(rec, k);
            const int v0 = r0 & 0x1FFFF, ul0 = r0 >> 17;
            const float d0 = data[(size_t)v0 * D_OUT + lane];
            const float raw0 = s_lds[ul0] + t[v0];
            const float l0 = raw0 > 0.f ? raw0 : 0.2f * raw0;
            const float w0 = __expf(l0 * 0.125f);
            atomicAdd(&acc[(ul0 << 6) + lane], w0 * d0);
            if (lane == 0) atomicAdd(&wsum[ul0], w0);
        }
    }
    __syncthreads();

    for (int ul = wv; ul < FB_NODES; ul += 4) {
        const int u = u0 + ul;
        if (u < n) {
            const float rs = wsum[ul];
            const float o = (rs == 0.f) ? data[(size_t)u * D_OUT + lane]
                                        : acc[(ul << 6) + lane] / rs;
            out[(size_t)u * D_OUT + lane] = o;
        }
    }
}

extern "C" void kernel_launch(void* const* d_in, const int* in_sizes, int n_in,
                              void* d_out, int out_size, void* d_ws, size_t ws_size,
                              hipStream_t stream)
{
    const float* h    = (const float*)d_in[0];
    const int*   edge = (const int*)d_in[1];
    const float* Ww   = (const float*)d_in[2];
    const float* Wb   = (const float*)d_in[3];
    const float* a    = (const float*)d_in[4];

    const int n  = in_sizes[0] / D_IN;    // 100000
    const int ne = in_sizes[1] / 2;       // 1600000

    const int* e0a = edge;
    const int* e1a = edge + ne;
    float* out = (float*)d_out;

    const int NB1 = (n + CB_NODES - 1) / CB_NODES;   // 98
    const int NF  = NB1 * FB_PER_CB;                 // 1568

    char* wsp = (char*)d_ws;
    float* data    = (float*)wsp;        wsp += (size_t)n * D_OUT * sizeof(float);
    float* s       = (float*)wsp;        wsp += (size_t)n * sizeof(float);
    float* t       = (float*)wsp;        wsp += (size_t)n * sizeof(float);
    int*   cursor1 = (int*)wsp;          wsp += 128 * sizeof(int);
    int*   cursor2 = (int*)wsp;          wsp += (size_t)NF * sizeof(int);
    unsigned int* region1 = (unsigned int*)wsp; wsp += (size_t)NB1 * CAP1 * sizeof(unsigned int);
    unsigned int* region2 = (unsigned int*)wsp; wsp += (size_t)NF * CAP2 * sizeof(unsigned int);

    hipMemsetAsync(cursor1, 0, (128 + (size_t)NF) * sizeof(int), stream);

    proj_kernel<<<(n + TILE_R - 1) / TILE_R, 256, 0, stream>>>(
        h, Ww, Wb, a, data, s, t, n);

    bin1_kernel<<<(ne + CHUNK1 - 1) / CHUNK1, 256, 0, stream>>>(
        e0a, e1a, cursor1, region1, ne);

    bin2_kernel<<<NB1 * 8, 256, 0, stream>>>(
        cursor1, region1, cursor2, region2);

    agg_kernel<<<NF, 256, 0, stream>>>(
        cursor2, region2, s, t, data, out, n);
}

// Round 5
// 398.116 us; speedup vs baseline: 2.3130x; 2.1484x over previous
//
#include <hip/hip_runtime.h>
#include <hip/hip_bf16.h>

#define D_IN   128
#define D_OUT  64
#define TILE_R 16

#define CB_NODES  1024     // nodes per coarse bucket
#define NB1       98       // ceil(100000/1024)
#define CAP1      20480    // coarse region slots (mean ~16327, +32 sigma)
#define CHUNK1    2048     // edges per bin1 block

// ---------------------------------------------------------------------------
// Kernel 1: data = h @ W^T + b ; s = data @ a_src ; t = data @ a_dst
// ---------------------------------------------------------------------------
__global__ __launch_bounds__(256) void proj_kernel(
    const float* __restrict__ h, const float* __restrict__ Ww,
    const float* __restrict__ Wb, const float* __restrict__ a,
    float* __restrict__ data, float* __restrict__ s_out, float* __restrict__ t_out,
    int n)
{
    __shared__ float  wt[D_IN][D_OUT + 1];
    __shared__ float4 hs4[TILE_R][D_IN / 4];

    const int tid = threadIdx.x;

    for (int i = tid; i < D_OUT * D_IN; i += 256) {
        int c = i >> 7;
        int k = i & (D_IN - 1);
        wt[k][c] = Ww[i];
    }

    const int r0 = blockIdx.x * TILE_R;
    for (int i = tid; i < TILE_R * (D_IN / 4); i += 256) {
        int r  = i >> 5;
        int kq = i & 31;
        float4 v = make_float4(0.f, 0.f, 0.f, 0.f);
        if (r0 + r < n)
            v = ((const float4*)h)[(size_t)(r0 + r) * (D_IN / 4) + kq];
        hs4[r][kq] = v;
    }
    __syncthreads();

    const int c    = tid & 63;
    const int wave = tid >> 6;
    const int rb   = wave * 4;
    const float a_src_c = a[c];
    const float a_dst_c = a[D_OUT + c];
    const float bias_c  = Wb[c];

    float acc0 = 0.f, acc1 = 0.f, acc2 = 0.f, acc3 = 0.f;
    #pragma unroll
    for (int kq = 0; kq < D_IN / 4; ++kq) {
        const float w0 = wt[4 * kq + 0][c];
        const float w1 = wt[4 * kq + 1][c];
        const float w2 = wt[4 * kq + 2][c];
        const float w3 = wt[4 * kq + 3][c];
        const float4 h0 = hs4[rb + 0][kq];
        const float4 h1 = hs4[rb + 1][kq];
        const float4 h2 = hs4[rb + 2][kq];
        const float4 h3 = hs4[rb + 3][kq];
        acc0 = fmaf(h0.x, w0, fmaf(h0.y, w1, fmaf(h0.z, w2, fmaf(h0.w, w3, acc0))));
        acc1 = fmaf(h1.x, w0, fmaf(h1.y, w1, fmaf(h1.z, w2, fmaf(h1.w, w3, acc1))));
        acc2 = fmaf(h2.x, w0, fmaf(h2.y, w1, fmaf(h2.z, w2, fmaf(h2.w, w3, acc2))));
        acc3 = fmaf(h3.x, w0, fmaf(h3.y, w1, fmaf(h3.z, w2, fmaf(h3.w, w3, acc3))));
    }

    float accs[4] = {acc0 + bias_c, acc1 + bias_c, acc2 + bias_c, acc3 + bias_c};
    #pragma unroll
    for (int q = 0; q < 4; ++q) {
        const int r = r0 + rb + q;
        const float acc = accs[q];
        if (r < n) data[(size_t)r * D_OUT + c] = acc;

        float sp = acc * a_src_c;
        float tp = acc * a_dst_c;
        #pragma unroll
        for (int off = 32; off > 0; off >>= 1) {
            sp += __shfl_xor(sp, off);
            tp += __shfl_xor(tp, off);
        }
        if (c == 0 && r < n) { s_out[r] = sp; t_out[r] = tp; }
    }
}

// ---------------------------------------------------------------------------
// bin1 (+ fused per-node histogram): edges -> 98 coarse buckets.
// Record = (u_local10 << 17) | e1
// ---------------------------------------------------------------------------
__global__ __launch_bounds__(256) void bin1_kernel(
    const int* __restrict__ e0a, const int* __restrict__ e1a,
    int* __restrict__ counts, int* __restrict__ cursor1,
    unsigned int* __restrict__ region1, int ne)
{
    __shared__ int cnt[128];
    __shared__ int basev[128];

    const int tid  = threadIdx.x;
    const int base = blockIdx.x * CHUNK1;

    for (int i = tid; i < 128; i += 256) cnt[i] = 0;
    __syncthreads();

    int bj[8]; unsigned rc[8];
    #pragma unroll
    for (int j = 0; j < 8; ++j) {
        const int i = base + j * 256 + tid;
        if (i < ne) {
            const int u = e0a[i];
            const int v = e1a[i];
            bj[j] = u >> 10;
            rc[j] = ((unsigned)(u & (CB_NODES - 1)) << 17) | (unsigned)v;
            atomicAdd(&cnt[bj[j]], 1);
            atomicAdd(&counts[u], 1);
        } else bj[j] = -1;
    }
    __syncthreads();

    for (int b = tid; b < 128; b += 256) {
        const int c = cnt[b];
        basev[b] = (c > 0) ? atomicAdd(&cursor1[b], c) : 0;
        cnt[b] = 0;
    }
    __syncthreads();

    #pragma unroll
    for (int j = 0; j < 8; ++j) {
        if (bj[j] >= 0) {
            const int p = basev[bj[j]] + atomicAdd(&cnt[bj[j]], 1);
            if (p < CAP1) region1[(size_t)bj[j] * CAP1 + p] = rc[j];
        }
    }
}

// ---------------------------------------------------------------------------
// Exclusive scan of counts -> offs (+cursor copy). 3 stages, from Round 2.
// ---------------------------------------------------------------------------
__global__ __launch_bounds__(256) void scan1_kernel(
    const int* __restrict__ counts, int* __restrict__ offs,
    int* __restrict__ bsums, int n)
{
    __shared__ int wsum[4];
    const int tid  = threadIdx.x;
    const int base = blockIdx.x * 1024 + tid * 4;

    int v0 = (base + 0 < n) ? counts[base + 0] : 0;
    int v1 = (base + 1 < n) ? counts[base + 1] : 0;
    int v2 = (base + 2 < n) ? counts[base + 2] : 0;
    int v3 = (base + 3 < n) ? counts[base + 3] : 0;
    const int tsum = v0 + v1 + v2 + v3;

    int x = tsum;
    #pragma unroll
    for (int off = 1; off < 64; off <<= 1) {
        int y = __shfl_up(x, off);
        if ((tid & 63) >= off) x += y;
    }
    const int wave = tid >> 6;
    if ((tid & 63) == 63) wsum[wave] = x;
    __syncthreads();

    int wofs = 0;
    #pragma unroll
    for (int w = 0; w < 4; ++w) if (w < wave) wofs += wsum[w];
    const int tofs = wofs + x - tsum;

    if (base + 0 < n) offs[base + 0] = tofs;
    if (base + 1 < n) offs[base + 1] = tofs + v0;
    if (base + 2 < n) offs[base + 2] = tofs + v0 + v1;
    if (base + 3 < n) offs[base + 3] = tofs + v0 + v1 + v2;
    if (tid == 0) bsums[blockIdx.x] = wsum[0] + wsum[1] + wsum[2] + wsum[3];
}

__global__ __launch_bounds__(256) void scan2_kernel(int* __restrict__ bsums, int nb)
{
    __shared__ int wsum[4];
    const int tid = threadIdx.x;
    const int v = (tid < nb) ? bsums[tid] : 0;
    int x = v;
    #pragma unroll
    for (int off = 1; off < 64; off <<= 1) {
        int y = __shfl_up(x, off);
        if ((tid & 63) >= off) x += y;
    }
    const int wave = tid >> 6;
    if ((tid & 63) == 63) wsum[wave] = x;
    __syncthreads();
    int wofs = 0;
    #pragma unroll
    for (int w = 0; w < 4; ++w) if (w < wave) wofs += wsum[w];
    if (tid < nb) bsums[tid] = wofs + x - v;
}

__global__ __launch_bounds__(256) void scan3_kernel(
    int* __restrict__ offs, const int* __restrict__ bsums,
    int* __restrict__ cursor, int n)
{
    const int b = bsums[blockIdx.x];
    const int base = blockIdx.x * 1024 + threadIdx.x;
    #pragma unroll
    for (int j = 0; j < 4; ++j) {
        int idx = base + j * 256;
        if (idx < n) {
            int o = offs[idx] + b;
            offs[idx] = o;
            cursor[idx] = o;
        }
    }
}

// ---------------------------------------------------------------------------
// scatter2: one 1024-thread block per coarse bucket. All se1 writes land in
// a 65 KB window; all cursor atomics in a 4 KB window (L2-resident).
// ---------------------------------------------------------------------------
__global__ __launch_bounds__(1024) void scatter2_kernel(
    const int* __restrict__ cursor1, const unsigned int* __restrict__ region1,
    int* __restrict__ cursor, int* __restrict__ se1)
{
    const int b    = blockIdx.x;
    const int cnt1 = min(cursor1[b], CAP1);
    const unsigned int* reg = region1 + (size_t)b * CAP1;
    const int u0 = b << 10;

    for (int i = threadIdx.x; i < cnt1; i += 1024) {
        const unsigned r = reg[i];
        const int u = u0 + (int)(r >> 17);
        const int v = (int)(r & 0x1FFFFu);
        const int pos = atomicAdd(&cursor[u], 1);
        se1[pos] = v;
    }
}

// ---------------------------------------------------------------------------
// Node aggregation: one wave per node, lane = feature, unroll-4 gathers.
// ---------------------------------------------------------------------------
__global__ __launch_bounds__(256) void node_kernel(
    const int* __restrict__ se1, const int* __restrict__ offs,
    const int* __restrict__ counts,
    const float* __restrict__ s, const float* __restrict__ t,
    const float* __restrict__ data, float* __restrict__ out, int n)
{
    const int wave = threadIdx.x >> 6;
    const int lane = threadIdx.x & 63;
    const int u = blockIdx.x * 4 + wave;
    if (u >= n) return;

    const int start = offs[u];
    const int deg   = counts[u];
    const float su  = s[u];

    float acc = 0.0f, wsum = 0.0f;

    int j = 0;
    for (; j + 4 <= deg; j += 4) {
        const int v0 = se1[start + j + 0];
        const int v1 = se1[start + j + 1];
        const int v2 = se1[start + j + 2];
        const int v3 = se1[start + j + 3];
        const float t0 = t[v0];
        const float t1 = t[v1];
        const float t2 = t[v2];
        const float t3 = t[v3];
        const float d0 = data[(size_t)v0 * D_OUT + lane];
        const float d1 = data[(size_t)v1 * D_OUT + lane];
        const float d2 = data[(size_t)v2 * D_OUT + lane];
        const float d3 = data[(size_t)v3 * D_OUT + lane];

        const float r0 = su + t0;
        const float r1 = su + t1;
        const float r2 = su + t2;
        const float r3 = su + t3;
        const float l0 = r0 > 0.0f ? r0 : 0.2f * r0;
        const float l1 = r1 > 0.0f ? r1 : 0.2f * r1;
        const float l2 = r2 > 0.0f ? r2 : 0.2f * r2;
        const float l3 = r3 > 0.0f ? r3 : 0.2f * r3;
        const float w0 = __expf(l0 * 0.125f);
        const float w1 = __expf(l1 * 0.125f);
        const float w2 = __expf(l2 * 0.125f);
        const float w3 = __expf(l3 * 0.125f);

        wsum += (w0 + w1) + (w2 + w3);
        acc = fmaf(w0, d0, acc);
        acc = fmaf(w1, d1, acc);
        acc = fmaf(w2, d2, acc);
        acc = fmaf(w3, d3, acc);
    }
    for (; j < deg; ++j) {
        const int v0 = se1[start + j];
        const float d0 = data[(size_t)v0 * D_OUT + lane];
        const float r0 = su + t[v0];
        const float l0 = r0 > 0.0f ? r0 : 0.2f * r0;
        const float w0 = __expf(l0 * 0.125f);
        wsum += w0;
        acc = fmaf(w0, d0, acc);
    }

    float o;
    if (deg == 0) o = data[(size_t)u * D_OUT + lane];
    else          o = acc / wsum;
    out[(size_t)u * D_OUT + lane] = o;
}

extern "C" void kernel_launch(void* const* d_in, const int* in_sizes, int n_in,
                              void* d_out, int out_size, void* d_ws, size_t ws_size,
                              hipStream_t stream)
{
    const float* h    = (const float*)d_in[0];
    const int*   edge = (const int*)d_in[1];
    const float* Ww   = (const float*)d_in[2];
    const float* Wb   = (const float*)d_in[3];
    const float* a    = (const float*)d_in[4];

    const int n  = in_sizes[0] / D_IN;    // 100000
    const int ne = in_sizes[1] / 2;       // 1600000

    const int* e0a = edge;
    const int* e1a = edge + ne;
    float* out = (float*)d_out;

    char* wsp = (char*)d_ws;
    float* data    = (float*)wsp;  wsp += (size_t)n * D_OUT * sizeof(float);
    float* s       = (float*)wsp;  wsp += (size_t)n * sizeof(float);
    float* t       = (float*)wsp;  wsp += (size_t)n * sizeof(float);
    int*   counts  = (int*)wsp;    wsp += (size_t)n * sizeof(int);
    int*   cursor1 = (int*)wsp;    wsp += 128 * sizeof(int);          // contiguous w/ counts
    int*   offs    = (int*)wsp;    wsp += (size_t)n * sizeof(int);
    int*   cursor  = (int*)wsp;    wsp += (size_t)n * sizeof(int);
    int*   bsums   = (int*)wsp;    wsp += 1024 * sizeof(int);
    unsigned int* region1 = (unsigned int*)wsp; wsp += (size_t)NB1 * CAP1 * sizeof(unsigned int);
    int*   se1     = (int*)wsp;    wsp += (size_t)ne * sizeof(int);

    const int nb = (n + 1023) / 1024;     // 98 scan blocks

    hipMemsetAsync(counts, 0, ((size_t)n + 128) * sizeof(int), stream);

    proj_kernel<<<(n + TILE_R - 1) / TILE_R, 256, 0, stream>>>(
        h, Ww, Wb, a, data, s, t, n);

    bin1_kernel<<<(ne + CHUNK1 - 1) / CHUNK1, 256, 0, stream>>>(
        e0a, e1a, counts, cursor1, region1, ne);

    scan1_kernel<<<nb, 256, 0, stream>>>(counts, offs, bsums, n);
    scan2_kernel<<<1, 256, 0, stream>>>(bsums, nb);
    scan3_kernel<<<nb, 256, 0, stream>>>(offs, bsums, cursor, n);

    scatter2_kernel<<<NB1, 1024, 0, stream>>>(cursor1, region1, cursor, se1);

    node_kernel<<<(n + 3) / 4, 256, 0, stream>>>(
        se1, offs, counts, s, t, data, out, n);
}

// Round 6
// 281.319 us; speedup vs baseline: 3.2733x; 1.4152x over previous
//
#include <hip/hip_runtime.h>
#include <hip/hip_bf16.h>

#define D_IN   128
#define D_OUT  64

#define CB_NODES  1024     // nodes per coarse bucket
#define NB1       98       // ceil(100000/1024)
#define CAP1      20480    // coarse region slots (mean ~16327, +32 sigma)
#define CHUNK1    2048     // edges per bin1 block

// ---------------------------------------------------------------------------
// W prep: wT[k][c] = W[c][k]  (8192 floats)
// ---------------------------------------------------------------------------
__global__ __launch_bounds__(256) void wprep_kernel(
    const float* __restrict__ Ww, float* __restrict__ wT)
{
    const int i = blockIdx.x * 256 + threadIdx.x;
    if (i < D_IN * D_OUT) {
        const int k = i >> 6;
        const int c = i & 63;
        wT[i] = Ww[c * D_IN + k];
    }
}

// ---------------------------------------------------------------------------
// Projection: lane-per-row. 64 accumulators/lane; W rows come in through the
// scalar pipe (lane-invariant addresses); h row chunks in 8 float4 regs.
// ---------------------------------------------------------------------------
__global__ __launch_bounds__(256, 4) void proj_kernel(
    const float* __restrict__ h, const float* __restrict__ wT,
    const float* __restrict__ Wb, const float* __restrict__ a,
    float* __restrict__ data, float* __restrict__ s_out, float* __restrict__ t_out,
    int n)
{
    const int row = blockIdx.x * 256 + threadIdx.x;
    if (row >= n) return;

    const float4* __restrict__ hrow = (const float4*)(h + (size_t)row * D_IN);

    float acc[D_OUT];
    #pragma unroll
    for (int c = 0; c < D_OUT; ++c) acc[c] = Wb[c];

    #pragma unroll 1
    for (int ch = 0; ch < 4; ++ch) {
        float4 hq[8];
        #pragma unroll
        for (int q = 0; q < 8; ++q) hq[q] = hrow[ch * 8 + q];

        #pragma unroll
        for (int q = 0; q < 8; ++q) {
            const float hv0 = hq[q].x, hv1 = hq[q].y, hv2 = hq[q].z, hv3 = hq[q].w;
            const int k0 = ch * 32 + q * 4;
            const float* __restrict__ w0 = wT + (size_t)(k0 + 0) * D_OUT;
            const float* __restrict__ w1 = wT + (size_t)(k0 + 1) * D_OUT;
            const float* __restrict__ w2 = wT + (size_t)(k0 + 2) * D_OUT;
            const float* __restrict__ w3 = wT + (size_t)(k0 + 3) * D_OUT;
            #pragma unroll
            for (int c = 0; c < D_OUT; ++c)
                acc[c] = fmaf(hv3, w3[c],
                         fmaf(hv2, w2[c],
                         fmaf(hv1, w1[c],
                         fmaf(hv0, w0[c], acc[c]))));
        }
    }

    // s = acc . a_src ; t = acc . a_dst  (a[] is lane-invariant)
    float sp = 0.f, tp = 0.f;
    #pragma unroll
    for (int c = 0; c < D_OUT; ++c) {
        sp = fmaf(acc[c], a[c], sp);
        tp = fmaf(acc[c], a[D_OUT + c], tp);
    }
    s_out[row] = sp;
    t_out[row] = tp;

    float4* __restrict__ drow = (float4*)(data + (size_t)row * D_OUT);
    #pragma unroll
    for (int q = 0; q < 16; ++q)
        drow[q] = make_float4(acc[4*q], acc[4*q+1], acc[4*q+2], acc[4*q+3]);
}

// ---------------------------------------------------------------------------
// bin1 (+ fused per-node histogram): edges -> 98 coarse buckets.
// Record = (u_local10 << 17) | e1
// ---------------------------------------------------------------------------
__global__ __launch_bounds__(256) void bin1_kernel(
    const int* __restrict__ e0a, const int* __restrict__ e1a,
    int* __restrict__ counts, int* __restrict__ cursor1,
    unsigned int* __restrict__ region1, int ne)
{
    __shared__ int cnt[128];
    __shared__ int basev[128];

    const int tid  = threadIdx.x;
    const int base = blockIdx.x * CHUNK1;

    for (int i = tid; i < 128; i += 256) cnt[i] = 0;
    __syncthreads();

    int bj[8]; unsigned rc[8];
    #pragma unroll
    for (int j = 0; j < 8; ++j) {
        const int i = base + j * 256 + tid;
        if (i < ne) {
            const int u = e0a[i];
            const int v = e1a[i];
            bj[j] = u >> 10;
            rc[j] = ((unsigned)(u & (CB_NODES - 1)) << 17) | (unsigned)v;
            atomicAdd(&cnt[bj[j]], 1);
            atomicAdd(&counts[u], 1);
        } else bj[j] = -1;
    }
    __syncthreads();

    for (int b = tid; b < 128; b += 256) {
        const int c = cnt[b];
        basev[b] = (c > 0) ? atomicAdd(&cursor1[b], c) : 0;
        cnt[b] = 0;
    }
    __syncthreads();

    #pragma unroll
    for (int j = 0; j < 8; ++j) {
        if (bj[j] >= 0) {
            const int p = basev[bj[j]] + atomicAdd(&cnt[bj[j]], 1);
            if (p < CAP1) region1[(size_t)bj[j] * CAP1 + p] = rc[j];
        }
    }
}

// ---------------------------------------------------------------------------
// Exclusive scan of counts -> offs (+cursor copy). 3 stages.
// ---------------------------------------------------------------------------
__global__ __launch_bounds__(256) void scan1_kernel(
    const int* __restrict__ counts, int* __restrict__ offs,
    int* __restrict__ bsums, int n)
{
    __shared__ int wsum[4];
    const int tid  = threadIdx.x;
    const int base = blockIdx.x * 1024 + tid * 4;

    int v0 = (base + 0 < n) ? counts[base + 0] : 0;
    int v1 = (base + 1 < n) ? counts[base + 1] : 0;
    int v2 = (base + 2 < n) ? counts[base + 2] : 0;
    int v3 = (base + 3 < n) ? counts[base + 3] : 0;
    const int tsum = v0 + v1 + v2 + v3;

    int x = tsum;
    #pragma unroll
    for (int off = 1; off < 64; off <<= 1) {
        int y = __shfl_up(x, off);
        if ((tid & 63) >= off) x += y;
    }
    const int wave = tid >> 6;
    if ((tid & 63) == 63) wsum[wave] = x;
    __syncthreads();

    int wofs = 0;
    #pragma unroll
    for (int w = 0; w < 4; ++w) if (w < wave) wofs += wsum[w];
    const int tofs = wofs + x - tsum;

    if (base + 0 < n) offs[base + 0] = tofs;
    if (base + 1 < n) offs[base + 1] = tofs + v0;
    if (base + 2 < n) offs[base + 2] = tofs + v0 + v1;
    if (base + 3 < n) offs[base + 3] = tofs + v0 + v1 + v2;
    if (tid == 0) bsums[blockIdx.x] = wsum[0] + wsum[1] + wsum[2] + wsum[3];
}

__global__ __launch_bounds__(256) void scan2_kernel(int* __restrict__ bsums, int nb)
{
    __shared__ int wsum[4];
    const int tid = threadIdx.x;
    const int v = (tid < nb) ? bsums[tid] : 0;
    int x = v;
    #pragma unroll
    for (int off = 1; off < 64; off <<= 1) {
        int y = __shfl_up(x, off);
        if ((tid & 63) >= off) x += y;
    }
    const int wave = tid >> 6;
    if ((tid & 63) == 63) wsum[wave] = x;
    __syncthreads();
    int wofs = 0;
    #pragma unroll
    for (int w = 0; w < 4; ++w) if (w < wave) wofs += wsum[w];
    if (tid < nb) bsums[tid] = wofs + x - v;
}

__global__ __launch_bounds__(256) void scan3_kernel(
    int* __restrict__ offs, const int* __restrict__ bsums,
    int* __restrict__ cursor, int n)
{
    const int b = bsums[blockIdx.x];
    const int base = blockIdx.x * 1024 + threadIdx.x;
    #pragma unroll
    for (int j = 0; j < 4; ++j) {
        int idx = base + j * 256;
        if (idx < n) {
            int o = offs[idx] + b;
            offs[idx] = o;
            cursor[idx] = o;
        }
    }
}

// ---------------------------------------------------------------------------
// scatter2: one 1024-thread block per coarse bucket; writes land in a 65 KB
// window, cursor atomics in a 4 KB window (L2-resident).
// ---------------------------------------------------------------------------
__global__ __launch_bounds__(1024) void scatter2_kernel(
    const int* __restrict__ cursor1, const unsigned int* __restrict__ region1,
    int* __restrict__ cursor, int* __restrict__ se1)
{
    const int b    = blockIdx.x;
    const int cnt1 = min(cursor1[b], CAP1);
    const unsigned int* reg = region1 + (size_t)b * CAP1;
    const int u0 = b << 10;

    for (int i = threadIdx.x; i < cnt1; i += 1024) {
        const unsigned r = reg[i];
        const int u = u0 + (int)(r >> 17);
        const int v = (int)(r & 0x1FFFFu);
        const int pos = atomicAdd(&cursor[u], 1);
        se1[pos] = v;
    }
}

// ---------------------------------------------------------------------------
// Node aggregation: one wave per node, lane = feature, unroll-4 gathers.
// ---------------------------------------------------------------------------
__global__ __launch_bounds__(256) void node_kernel(
    const int* __restrict__ se1, const int* __restrict__ offs,
    const int* __restrict__ counts,
    const float* __restrict__ s, const float* __restrict__ t,
    const float* __restrict__ data, float* __restrict__ out, int n)
{
    const int wave = threadIdx.x >> 6;
    const int lane = threadIdx.x & 63;
    const int u = blockIdx.x * 4 + wave;
    if (u >= n) return;

    const int start = offs[u];
    const int deg   = counts[u];
    const float su  = s[u];

    float acc = 0.0f, wsum = 0.0f;

    int j = 0;
    for (; j + 4 <= deg; j += 4) {
        const int v0 = se1[start + j + 0];
        const int v1 = se1[start + j + 1];
        const int v2 = se1[start + j + 2];
        const int v3 = se1[start + j + 3];
        const float t0 = t[v0];
        const float t1 = t[v1];
        const float t2 = t[v2];
        const float t3 = t[v3];
        const float d0 = data[(size_t)v0 * D_OUT + lane];
        const float d1 = data[(size_t)v1 * D_OUT + lane];
        const float d2 = data[(size_t)v2 * D_OUT + lane];
        const float d3 = data[(size_t)v3 * D_OUT + lane];

        const float r0 = su + t0;
        const float r1 = su + t1;
        const float r2 = su + t2;
        const float r3 = su + t3;
        const float l0 = r0 > 0.0f ? r0 : 0.2f * r0;
        const float l1 = r1 > 0.0f ? r1 : 0.2f * r1;
        const float l2 = r2 > 0.0f ? r2 : 0.2f * r2;
        const float l3 = r3 > 0.0f ? r3 : 0.2f * r3;
        const float w0 = __expf(l0 * 0.125f);
        const float w1 = __expf(l1 * 0.125f);
        const float w2 = __expf(l2 * 0.125f);
        const float w3 = __expf(l3 * 0.125f);

        wsum += (w0 + w1) + (w2 + w3);
        acc = fmaf(w0, d0, acc);
        acc = fmaf(w1, d1, acc);
        acc = fmaf(w2, d2, acc);
        acc = fmaf(w3, d3, acc);
    }
    for (; j < deg; ++j) {
        const int v0 = se1[start + j];
        const float d0 = data[(size_t)v0 * D_OUT + lane];
        const float r0 = su + t[v0];
        const float l0 = r0 > 0.0f ? r0 : 0.2f * r0;
        const float w0 = __expf(l0 * 0.125f);
        wsum += w0;
        acc = fmaf(w0, d0, acc);
    }

    float o;
    if (deg == 0) o = data[(size_t)u * D_OUT + lane];
    else          o = acc / wsum;
    out[(size_t)u * D_OUT + lane] = o;
}

extern "C" void kernel_launch(void* const* d_in, const int* in_sizes, int n_in,
                              void* d_out, int out_size, void* d_ws, size_t ws_size,
                              hipStream_t stream)
{
    const float* h    = (const float*)d_in[0];
    const int*   edge = (const int*)d_in[1];
    const float* Ww   = (const float*)d_in[2];
    const float* Wb   = (const float*)d_in[3];
    const float* a    = (const float*)d_in[4];

    const int n  = in_sizes[0] / D_IN;    // 100000
    const int ne = in_sizes[1] / 2;       // 1600000

    const int* e0a = edge;
    const int* e1a = edge + ne;
    float* out = (float*)d_out;

    char* wsp = (char*)d_ws;
    float* data    = (float*)wsp;  wsp += (size_t)n * D_OUT * sizeof(float);
    float* s       = (float*)wsp;  wsp += (size_t)n * sizeof(float);
    float* t       = (float*)wsp;  wsp += (size_t)n * sizeof(float);
    int*   counts  = (int*)wsp;    wsp += (size_t)n * sizeof(int);
    int*   cursor1 = (int*)wsp;    wsp += 128 * sizeof(int);          // contiguous w/ counts
    int*   offs    = (int*)wsp;    wsp += (size_t)n * sizeof(int);
    int*   cursor  = (int*)wsp;    wsp += (size_t)n * sizeof(int);
    int*   bsums   = (int*)wsp;    wsp += 1024 * sizeof(int);
    float* wT      = (float*)wsp;  wsp += (size_t)D_IN * D_OUT * sizeof(float);
    unsigned int* region1 = (unsigned int*)wsp; wsp += (size_t)NB1 * CAP1 * sizeof(unsigned int);
    int*   se1     = (int*)wsp;    wsp += (size_t)ne * sizeof(int);

    const int nb = (n + 1023) / 1024;     // 98 scan blocks

    hipMemsetAsync(counts, 0, ((size_t)n + 128) * sizeof(int), stream);

    wprep_kernel<<<(D_IN * D_OUT + 255) / 256, 256, 0, stream>>>(Ww, wT);

    proj_kernel<<<(n + 255) / 256, 256, 0, stream>>>(
        h, wT, Wb, a, data, s, t, n);

    bin1_kernel<<<(ne + CHUNK1 - 1) / CHUNK1, 256, 0, stream>>>(
        e0a, e1a, counts, cursor1, region1, ne);

    scan1_kernel<<<nb, 256, 0, stream>>>(counts, offs, bsums, n);
    scan2_kernel<<<1, 256, 0, stream>>>(bsums, nb);
    scan3_kernel<<<nb, 256, 0, stream>>>(offs, bsums, cursor, n);

    scatter2_kernel<<<NB1, 1024, 0, stream>>>(cursor1, region1, cursor, se1);

    node_kernel<<<(n + 3) / 4, 256, 0, stream>>>(
        se1, offs, counts, s, t, data, out, n);
}

// Round 7
// 180.953 us; speedup vs baseline: 5.0888x; 1.5546x over previous
//
#include <hip/hip_runtime.h>
#include <hip/hip_bf16.h>

#define D_IN   128
#define D_OUT  64

#define CB_NODES  1024     // nodes per coarse bucket
#define NB1       98       // ceil(100000/1024)
#define CAP1      20480    // coarse region slots (mean ~16327, +32 sigma)
#define CHUNK1    2048     // edges per bin1 block (1024 thr x 2)

// ---------------------------------------------------------------------------
// W prep: wT[k][c] = W[c][k]  (8192 floats)
// ---------------------------------------------------------------------------
__global__ __launch_bounds__(256) void wprep_kernel(
    const float* __restrict__ Ww, float* __restrict__ wT)
{
    const int i = blockIdx.x * 256 + threadIdx.x;
    if (i < D_IN * D_OUT) {
        const int k = i >> 6;
        const int c = i & 63;
        wT[i] = Ww[c * D_IN + k];
    }
}

// ---------------------------------------------------------------------------
// Projection: lane-per-row, scalar-pipe weights (lane-invariant addresses).
// ---------------------------------------------------------------------------
__global__ __launch_bounds__(256, 4) void proj_kernel(
    const float* __restrict__ h, const float* __restrict__ wT,
    const float* __restrict__ Wb, const float* __restrict__ a,
    float* __restrict__ data, float* __restrict__ s_out, float* __restrict__ t_out,
    int n)
{
    const int row = blockIdx.x * 256 + threadIdx.x;
    if (row >= n) return;

    const float4* __restrict__ hrow = (const float4*)(h + (size_t)row * D_IN);

    float acc[D_OUT];
    #pragma unroll
    for (int c = 0; c < D_OUT; ++c) acc[c] = Wb[c];

    #pragma unroll 1
    for (int ch = 0; ch < 4; ++ch) {
        float4 hq[8];
        #pragma unroll
        for (int q = 0; q < 8; ++q) hq[q] = hrow[ch * 8 + q];

        #pragma unroll
        for (int q = 0; q < 8; ++q) {
            const float hv0 = hq[q].x, hv1 = hq[q].y, hv2 = hq[q].z, hv3 = hq[q].w;
            const int k0 = ch * 32 + q * 4;
            const float* __restrict__ w0 = wT + (size_t)(k0 + 0) * D_OUT;
            const float* __restrict__ w1 = wT + (size_t)(k0 + 1) * D_OUT;
            const float* __restrict__ w2 = wT + (size_t)(k0 + 2) * D_OUT;
            const float* __restrict__ w3 = wT + (size_t)(k0 + 3) * D_OUT;
            #pragma unroll
            for (int c = 0; c < D_OUT; ++c)
                acc[c] = fmaf(hv3, w3[c],
                         fmaf(hv2, w2[c],
                         fmaf(hv1, w1[c],
                         fmaf(hv0, w0[c], acc[c]))));
        }
    }

    float sp = 0.f, tp = 0.f;
    #pragma unroll
    for (int c = 0; c < D_OUT; ++c) {
        sp = fmaf(acc[c], a[c], sp);
        tp = fmaf(acc[c], a[D_OUT + c], tp);
    }
    s_out[row] = sp;
    t_out[row] = tp;

    float4* __restrict__ drow = (float4*)(data + (size_t)row * D_OUT);
    #pragma unroll
    for (int q = 0; q < 16; ++q)
        drow[q] = make_float4(acc[4*q], acc[4*q+1], acc[4*q+2], acc[4*q+3]);
}

// ---------------------------------------------------------------------------
// bin1: edges -> 98 coarse buckets. Record = (u_local10 << 17) | e1.
// 1024 threads x 2 edges; no global histogram.
// ---------------------------------------------------------------------------
__global__ __launch_bounds__(1024) void bin1_kernel(
    const int* __restrict__ e0a, const int* __restrict__ e1a,
    int* __restrict__ cursor1, unsigned int* __restrict__ region1, int ne)
{
    __shared__ int cnt[128];
    __shared__ int basev[128];

    const int tid  = threadIdx.x;
    const int base = blockIdx.x * CHUNK1;

    if (tid < 128) cnt[tid] = 0;
    __syncthreads();

    int bj[2]; unsigned rc[2];
    #pragma unroll
    for (int j = 0; j < 2; ++j) {
        const int i = base + j * 1024 + tid;
        if (i < ne) {
            const int u = e0a[i];
            const int v = e1a[i];
            bj[j] = u >> 10;
            rc[j] = ((unsigned)(u & (CB_NODES - 1)) << 17) | (unsigned)v;
            atomicAdd(&cnt[bj[j]], 1);
        } else bj[j] = -1;
    }
    __syncthreads();

    if (tid < 128) {
        const int c = cnt[tid];
        basev[tid] = (c > 0) ? atomicAdd(&cursor1[tid], c) : 0;
        cnt[tid] = 0;
    }
    __syncthreads();

    #pragma unroll
    for (int j = 0; j < 2; ++j) {
        if (bj[j] >= 0) {
            const int p = basev[bj[j]] + atomicAdd(&cnt[bj[j]], 1);
            if (p < CAP1) region1[(size_t)bj[j] * CAP1 + p] = rc[j];
        }
    }
}

// ---------------------------------------------------------------------------
// bbase: exclusive scan of min(cursor1[b], CAP1) over 98 buckets (1 block).
// ---------------------------------------------------------------------------
__global__ __launch_bounds__(128) void bbase_kernel(
    const int* __restrict__ cursor1, int* __restrict__ bbase)
{
    __shared__ int wtot;
    const int tid  = threadIdx.x;
    const int lane = tid & 63;
    const int wv   = tid >> 6;
    const int v = (tid < NB1) ? min(cursor1[tid], CAP1) : 0;
    int x = v;
    #pragma unroll
    for (int off = 1; off < 64; off <<= 1) {
        int y = __shfl_up(x, off);
        if (lane >= off) x += y;
    }
    if (wv == 0 && lane == 63) wtot = x;
    __syncthreads();
    const int add = (wv == 1) ? wtot : 0;
    if (tid < NB1) bbase[tid] = add + x - v;
}

// ---------------------------------------------------------------------------
// Per-bucket CSR: one 1024-thread block per bucket. LDS histogram + scan,
// coalesced counts/offs write, local scatter into a 64 KB se1 window.
// ---------------------------------------------------------------------------
__global__ __launch_bounds__(1024) void bucket_csr_kernel(
    const int* __restrict__ cursor1, const unsigned int* __restrict__ region1,
    const int* __restrict__ bbase,
    int* __restrict__ counts, int* __restrict__ offs, int* __restrict__ se1, int n)
{
    __shared__ int lcnt[CB_NODES];
    __shared__ int loff[CB_NODES];
    __shared__ int wsum[16];

    const int b   = blockIdx.x;
    const int tid = threadIdx.x;
    const int cnt1 = min(cursor1[b], CAP1);
    const unsigned int* __restrict__ reg = region1 + (size_t)b * CAP1;
    const int u0 = b << 10;

    lcnt[tid] = 0;
    __syncthreads();

    for (int i = tid; i < cnt1; i += 1024)
        atomicAdd(&lcnt[reg[i] >> 17], 1);
    __syncthreads();

    // block-wide exclusive scan of lcnt[1024]
    const int lane = tid & 63;
    const int wv   = tid >> 6;
    const int v = lcnt[tid];
    int x = v;
    #pragma unroll
    for (int off = 1; off < 64; off <<= 1) {
        int y = __shfl_up(x, off);
        if (lane >= off) x += y;
    }
    if (lane == 63) wsum[wv] = x;
    __syncthreads();
    if (wv == 0) {
        const int wval = (lane < 16) ? wsum[lane] : 0;
        int wx = wval;
        #pragma unroll
        for (int off = 1; off < 16; off <<= 1) {
            int y = __shfl_up(wx, off);
            if (lane >= off) wx += y;
        }
        if (lane < 16) wsum[lane] = wx - wval;   // exclusive wave offsets
    }
    __syncthreads();
    const int excl = wsum[wv] + x - v;

    const int base = bbase[b];
    loff[tid] = excl;
    lcnt[tid] = 0;
    const int u = u0 + tid;
    if (u < n) { counts[u] = v; offs[u] = base + excl; }
    __syncthreads();

    for (int i = tid; i < cnt1; i += 1024) {
        const unsigned r = reg[i];
        const int ul = (int)(r >> 17);
        const int p  = base + loff[ul] + atomicAdd(&lcnt[ul], 1);
        se1[p] = (int)(r & 0x1FFFFu);
    }
}

// ---------------------------------------------------------------------------
// Node aggregation: one wave per node, lane = feature, unroll-4 gathers.
// ---------------------------------------------------------------------------
__global__ __launch_bounds__(256) void node_kernel(
    const int* __restrict__ se1, const int* __restrict__ offs,
    const int* __restrict__ counts,
    const float* __restrict__ s, const float* __restrict__ t,
    const float* __restrict__ data, float* __restrict__ out, int n)
{
    const int wave = threadIdx.x >> 6;
    const int lane = threadIdx.x & 63;
    const int u = blockIdx.x * 4 + wave;
    if (u >= n) return;

    const int start = offs[u];
    const int deg   = counts[u];
    const float su  = s[u];

    float acc = 0.0f, wsum = 0.0f;

    int j = 0;
    for (; j + 4 <= deg; j += 4) {
        const int v0 = se1[start + j + 0];
        const int v1 = se1[start + j + 1];
        const int v2 = se1[start + j + 2];
        const int v3 = se1[start + j + 3];
        const float t0 = t[v0];
        const float t1 = t[v1];
        const float t2 = t[v2];
        const float t3 = t[v3];
        const float d0 = data[(size_t)v0 * D_OUT + lane];
        const float d1 = data[(size_t)v1 * D_OUT + lane];
        const float d2 = data[(size_t)v2 * D_OUT + lane];
        const float d3 = data[(size_t)v3 * D_OUT + lane];

        const float r0 = su + t0;
        const float r1 = su + t1;
        const float r2 = su + t2;
        const float r3 = su + t3;
        const float l0 = r0 > 0.0f ? r0 : 0.2f * r0;
        const float l1 = r1 > 0.0f ? r1 : 0.2f * r1;
        const float l2 = r2 > 0.0f ? r2 : 0.2f * r2;
        const float l3 = r3 > 0.0f ? r3 : 0.2f * r3;
        const float w0 = __expf(l0 * 0.125f);
        const float w1 = __expf(l1 * 0.125f);
        const float w2 = __expf(l2 * 0.125f);
        const float w3 = __expf(l3 * 0.125f);

        wsum += (w0 + w1) + (w2 + w3);
        acc = fmaf(w0, d0, acc);
        acc = fmaf(w1, d1, acc);
        acc = fmaf(w2, d2, acc);
        acc = fmaf(w3, d3, acc);
    }
    for (; j < deg; ++j) {
        const int v0 = se1[start + j];
        const float d0 = data[(size_t)v0 * D_OUT + lane];
        const float r0 = su + t[v0];
        const float l0 = r0 > 0.0f ? r0 : 0.2f * r0;
        const float w0 = __expf(l0 * 0.125f);
        wsum += w0;
        acc = fmaf(w0, d0, acc);
    }

    float o;
    if (deg == 0) o = data[(size_t)u * D_OUT + lane];
    else          o = acc / wsum;
    out[(size_t)u * D_OUT + lane] = o;
}

extern "C" void kernel_launch(void* const* d_in, const int* in_sizes, int n_in,
                              void* d_out, int out_size, void* d_ws, size_t ws_size,
                              hipStream_t stream)
{
    const float* h    = (const float*)d_in[0];
    const int*   edge = (const int*)d_in[1];
    const float* Ww   = (const float*)d_in[2];
    const float* Wb   = (const float*)d_in[3];
    const float* a    = (const float*)d_in[4];

    const int n  = in_sizes[0] / D_IN;    // 100000
    const int ne = in_sizes[1] / 2;       // 1600000

    const int* e0a = edge;
    const int* e1a = edge + ne;
    float* out = (float*)d_out;

    char* wsp = (char*)d_ws;
    float* data    = (float*)wsp;  wsp += (size_t)n * D_OUT * sizeof(float);
    float* s       = (float*)wsp;  wsp += (size_t)n * sizeof(float);
    float* t       = (float*)wsp;  wsp += (size_t)n * sizeof(float);
    int*   counts  = (int*)wsp;    wsp += (size_t)n * sizeof(int);
    int*   offs    = (int*)wsp;    wsp += (size_t)n * sizeof(int);
    int*   cursor1 = (int*)wsp;    wsp += 128 * sizeof(int);
    int*   bbase   = (int*)wsp;    wsp += 128 * sizeof(int);
    float* wT      = (float*)wsp;  wsp += (size_t)D_IN * D_OUT * sizeof(float);
    unsigned int* region1 = (unsigned int*)wsp; wsp += (size_t)NB1 * CAP1 * sizeof(unsigned int);
    int*   se1     = (int*)wsp;    wsp += (size_t)ne * sizeof(int);

    hipMemsetAsync(cursor1, 0, 128 * sizeof(int), stream);

    wprep_kernel<<<(D_IN * D_OUT + 255) / 256, 256, 0, stream>>>(Ww, wT);

    proj_kernel<<<(n + 255) / 256, 256, 0, stream>>>(
        h, wT, Wb, a, data, s, t, n);

    bin1_kernel<<<(ne + CHUNK1 - 1) / CHUNK1, 1024, 0, stream>>>(
        e0a, e1a, cursor1, region1, ne);

    bbase_kernel<<<1, 128, 0, stream>>>(cursor1, bbase);

    bucket_csr_kernel<<<NB1, 1024, 0, stream>>>(
        cursor1, region1, bbase, counts, offs, se1, n);

    node_kernel<<<(n + 3) / 4, 256, 0, stream>>>(
        se1, offs, counts, s, t, data, out, n);
}